// Round 8
// baseline (292.447 us; speedup 1.0000x reference)
//
#include <hip/hip_runtime.h>
#include <hip/hip_bf16.h>
#include <stdint.h>

// MultiHeadAttention: B=2, S=2048, D=1024, H=16, DK=64, causal mask.
// R8: XCD-aware block swizzle for qkv/o_gemm (XCD owns 4 A-stripes -> A is
// L2-resident, fetched ~once); fp32->bf16 conversion fused into qkv staging
// (convert kernel now weights-only). attn unchanged from R7.

#define H_ 16
#define DM 1024
#define DK_ 64
#define BB 2
#define SS 2048
#define PSTR 72   // padded LDS stride (shorts) for P round-trip

typedef __bf16 bf16x8 __attribute__((ext_vector_type(8)));
typedef __bf16 bf16x2_t __attribute__((ext_vector_type(2)));
typedef float f32x4 __attribute__((ext_vector_type(4)));

#define GLOAD_LDS16(g, l)                                            \
  __builtin_amdgcn_global_load_lds(                                  \
      (__attribute__((address_space(1))) void*)(g),                  \
      (__attribute__((address_space(3))) void*)(l), 16, 0, 0)

__device__ __forceinline__ unsigned short f2bf_u(float f) {
  unsigned int u = __float_as_uint(f);
  u += 0x7fffu + ((u >> 16) & 1u);   // round-to-nearest-even
  return (unsigned short)(u >> 16);
}

__device__ __forceinline__ unsigned int pack_bf16(float a, float b) {
#if __has_builtin(__builtin_amdgcn_cvt_pk_bf16_f32)
  bf16x2_t v = __builtin_amdgcn_cvt_pk_bf16_f32(a, b);
  unsigned int u;
  __builtin_memcpy(&u, &v, 4);
  return u;
#else
  return (unsigned int)f2bf_u(a) | ((unsigned int)f2bf_u(b) << 16);
#endif
}

__device__ __forceinline__ float fexp2(float x) {
#if __has_builtin(__builtin_amdgcn_exp2f)
  return __builtin_amdgcn_exp2f(x);
#else
  return exp2f(x);
#endif
}

// --------------------------------------------------- convert (weights only)
struct Cvt {
  const float* s[4];
  unsigned short* d[4];
};

__global__ __launch_bounds__(256) void convert_kernel(Cvt c) {
  const int y = blockIdx.y;
  const float* __restrict__ src = c.s[y];
  unsigned short* __restrict__ dst = c.d[y];
  for (int i = blockIdx.x * 256 + threadIdx.x; i < (1 << 18); i += 256 * 256) {
    float4 v = *(const float4*)(src + (size_t)i * 4);
    ushort4 o;
    o.x = f2bf_u(v.x); o.y = f2bf_u(v.y); o.z = f2bf_u(v.z); o.w = f2bf_u(v.w);
    *(ushort4*)(dst + (size_t)i * 4) = o;
  }
}

// ----------------------------------------------- GEMM core (bf16 A staging)
template <int DUMMY = 0>
__device__ __forceinline__ void gemm_core(
    const unsigned short* __restrict__ A, const unsigned short* __restrict__ W,
    unsigned short* As, unsigned short* Bs, int m0, int n0, int k0, int k1,
    f32x4 (*acc)[4]) {
  const int tid = threadIdx.x;
  const int wave = tid >> 6, lane = tid & 63;
  const int lm = lane & 15, quad = lane >> 4;
  const int wm = (wave >> 1) * 64, wn = (wave & 1) * 64;
  const int srow = lane >> 2;
  const int scol = (lane & 3) * 8;

#pragma unroll
  for (int i = 0; i < 4; ++i)
#pragma unroll
    for (int j = 0; j < 4; ++j) {
      f32x4 z = {0.f, 0.f, 0.f, 0.f};
      acc[i][j] = z;
    }

  for (int kt = k0; kt < k1; kt += 32) {
#pragma unroll
    for (int cc = 0; cc < 2; ++cc) {
      int c = wave * 2 + cc;
      GLOAD_LDS16(A + (size_t)(m0 + c * 16 + srow) * DM + kt + scol,
                  As + c * 512 + lane * 8);
      GLOAD_LDS16(W + (size_t)(n0 + c * 16 + srow) * DM + kt + scol,
                  Bs + c * 512 + lane * 8);
    }
    __syncthreads();
    bf16x8 af[4], bfr[4];
#pragma unroll
    for (int i = 0; i < 4; ++i)
      af[i] = *(const bf16x8*)(As + (wm + i * 16 + lm) * 32 + quad * 8);
#pragma unroll
    for (int j = 0; j < 4; ++j)
      bfr[j] = *(const bf16x8*)(Bs + (wn + j * 16 + lm) * 32 + quad * 8);
#pragma unroll
    for (int i = 0; i < 4; ++i)
#pragma unroll
      for (int j = 0; j < 4; ++j)
        acc[i][j] = __builtin_amdgcn_mfma_f32_16x16x32_bf16(af[i], bfr[j],
                                                            acc[i][j], 0, 0, 0);
    __syncthreads();
  }
}

// ----------------------------------- GEMM core with fused fp32->bf16 A stage
// A tile row r, col c lives at LDS shorts [r*32 + c] (identical layout to the
// global_load_lds path, so fragment reads are unchanged).
template <int DUMMY = 0>
__device__ __forceinline__ void gemm_core_f32A(
    const float* __restrict__ A, const unsigned short* __restrict__ W,
    unsigned short* As, unsigned short* Bs, int m0, int n0,
    f32x4 (*acc)[4]) {
  const int tid = threadIdx.x;
  const int wave = tid >> 6, lane = tid & 63;
  const int lm = lane & 15, quad = lane >> 4;
  const int wm = (wave >> 1) * 64, wn = (wave & 1) * 64;
  const int srow = lane >> 2;
  const int scol = (lane & 3) * 8;
  const int arow = tid >> 1, acol = (tid & 1) * 16;   // A staging coords

#pragma unroll
  for (int i = 0; i < 4; ++i)
#pragma unroll
    for (int j = 0; j < 4; ++j) {
      f32x4 z = {0.f, 0.f, 0.f, 0.f};
      acc[i][j] = z;
    }

  for (int kt = 0; kt < DM; kt += 32) {
#pragma unroll
    for (int cc = 0; cc < 2; ++cc) {   // W: async global->LDS
      int c = wave * 2 + cc;
      GLOAD_LDS16(W + (size_t)(n0 + c * 16 + srow) * DM + kt + scol,
                  Bs + c * 512 + lane * 8);
    }
    // A: fp32 load -> packed bf16 -> LDS (16 floats / thread / iter)
    const float* ga = A + (size_t)(m0 + arow) * DM + kt + acol;
    float4 f0 = *(const float4*)(ga);
    float4 f1 = *(const float4*)(ga + 4);
    float4 f2 = *(const float4*)(ga + 8);
    float4 f3 = *(const float4*)(ga + 12);
    uint4 u0 = {pack_bf16(f0.x, f0.y), pack_bf16(f0.z, f0.w),
                pack_bf16(f1.x, f1.y), pack_bf16(f1.z, f1.w)};
    uint4 u1 = {pack_bf16(f2.x, f2.y), pack_bf16(f2.z, f2.w),
                pack_bf16(f3.x, f3.y), pack_bf16(f3.z, f3.w)};
    *(uint4*)(As + arow * 32 + acol) = u0;
    *(uint4*)(As + arow * 32 + acol + 8) = u1;
    __syncthreads();
    bf16x8 af[4], bfr[4];
#pragma unroll
    for (int i = 0; i < 4; ++i)
      af[i] = *(const bf16x8*)(As + (wm + i * 16 + lm) * 32 + quad * 8);
#pragma unroll
    for (int j = 0; j < 4; ++j)
      bfr[j] = *(const bf16x8*)(Bs + (wn + j * 16 + lm) * 32 + quad * 8);
#pragma unroll
    for (int i = 0; i < 4; ++i)
#pragma unroll
      for (int j = 0; j < 4; ++j)
        acc[i][j] = __builtin_amdgcn_mfma_f32_16x16x32_bf16(af[i], bfr[j],
                                                            acc[i][j], 0, 0, 0);
    __syncthreads();
  }
}

// fused Q/K/V projection, fp32 activations in, FRAGMENT-ORDERED outputs.
// 1D grid 768, XCD swizzle: c=p%8 owns A-stripes y in {4c..4c+3}.
// Qf/Kf layout: block (bh*128 + s/16)*2 + d64/32, pos ((d64%32)/8*16+s%16)*8+d64%8.
// Vf layout: block ((bh*32+s/64)*4+dk/16)*2+(s%64)/32, pos ((s%32)/8*16+dk%16)*8+s%8.
__global__ __launch_bounds__(256) void qkv_gemm(
    const float* q32, const float* k32, const float* v32,
    const unsigned short* Wq, const unsigned short* Wk, const unsigned short* Wv,
    const float* bq, const float* bk, const float* bv,
    unsigned short* Qf, unsigned short* Kf, unsigned short* Vf) {
  __shared__ unsigned short As[128 * 32], Bs[128 * 32];
  const int p = blockIdx.x;
  const int c = p & 7, jj0 = p >> 3;             // c = XCD
  const int x = jj0 & 7, yy = (jj0 >> 3) & 3, z = jj0 >> 5;
  const int y = c * 4 + yy;
  const int m0 = y * 128, n0 = x * 128;
  const float* A = z == 0 ? q32 : (z == 1 ? k32 : v32);
  const unsigned short* W = z == 0 ? Wq : (z == 1 ? Wk : Wv);
  const float* bias = z == 0 ? bq : (z == 1 ? bk : bv);
  const float scale = z == 0 ? 0.125f : 1.0f;    // fold 1/sqrt(64) into Q
  f32x4 acc[4][4];
  gemm_core_f32A(A, W, As, Bs, m0, n0, acc);
  const int lane = threadIdx.x & 63, wave = threadIdx.x >> 6;
  const int lm = lane & 15, quad = lane >> 4;
  const int wm = (wave >> 1) * 64, wn = (wave & 1) * 64;
  if (z == 2) {
#pragma unroll
    for (int j = 0; j < 4; ++j) {
      int gn = n0 + wn + j * 16 + lm;
      float bv_ = bias[gn];
      int h2 = gn >> 6, dk = gn & 63;
      int a = dk >> 4, ln = dk & 15;
#pragma unroll
      for (int i = 0; i < 4; ++i) {
        int s0 = m0 + wm + i * 16 + quad * 4;    // 4 consecutive s
        int b2 = s0 >> 11, sl = s0 & 2047;
        int kt2 = sl >> 6, cc = (sl >> 5) & 1, qk = (sl >> 3) & 3, j0 = sl & 7;
        size_t base =
            ((size_t)(((b2 * 16 + h2) * 32 + kt2) * 4 + a) * 2 + cc) * 512 +
            (qk * 16 + ln) * 8 + j0;
        uint2 w;
        w.x = pack_bf16(acc[i][j][0] + bv_, acc[i][j][1] + bv_);
        w.y = pack_bf16(acc[i][j][2] + bv_, acc[i][j][3] + bv_);
        *(uint2*)(Vf + base) = w;
      }
    }
  } else {
    unsigned short* out = z == 0 ? Qf : Kf;
#pragma unroll
    for (int j = 0; j < 4; ++j) {
      int gn = n0 + wn + j * 16 + lm;
      float bv_ = bias[gn];
      int h2 = gn >> 6, d64 = gn & 63;
      int cc = (d64 >> 5) & 1, qk = (d64 >> 3) & 3, jjq = d64 & 7;
#pragma unroll
      for (int i = 0; i < 4; ++i)
#pragma unroll
        for (int r = 0; r < 4; ++r) {
          int gm = m0 + wm + i * 16 + quad * 4 + r;
          int b2 = gm >> 11, sl = gm & 2047;
          size_t base =
              ((size_t)((b2 * 16 + h2) * 128 + (sl >> 4)) * 2 + cc) * 512 +
              (qk * 16 + (sl & 15)) * 8 + jjq;
          out[base] = f2bf_u((acc[i][j][r] + bv_) * scale);
        }
    }
  }
}

// O-projection split-K, XCD-swizzled (c=p%8 owns 4 Ctx stripes).
__global__ __launch_bounds__(256) void o_gemm_sk(
    const unsigned short* Ctx, const unsigned short* Wo,
    float* P0, float* P1) {
  __shared__ unsigned short As[128 * 32], Bs[128 * 32];
  const int p = blockIdx.x;
  const int c = p & 7, jj0 = p >> 3;
  const int x = jj0 & 7, yy = (jj0 >> 3) & 3, ks = jj0 >> 5;
  const int y = c * 4 + yy;
  const int m0 = y * 128, n0 = x * 128;
  f32x4 acc[4][4];
  gemm_core(Ctx, Wo, As, Bs, m0, n0, ks * 512, ks * 512 + 512, acc);
  const int lane = threadIdx.x & 63, wave = threadIdx.x >> 6;
  const int lm = lane & 15, quad = lane >> 4;
  const int wm = (wave >> 1) * 64, wn = (wave & 1) * 64;
  float* dst = ks ? P1 : P0;
#pragma unroll
  for (int j = 0; j < 4; ++j) {
    int gn = n0 + wn + j * 16 + lm;
#pragma unroll
    for (int i = 0; i < 4; ++i)
#pragma unroll
      for (int r = 0; r < 4; ++r) {
        int gm = m0 + wm + i * 16 + quad * 4 + r;
        dst[(size_t)gm * DM + gn] = acc[i][j][r];
      }
  }
}

__global__ __launch_bounds__(256) void o_reduce(
    const float4* __restrict__ P0, const float4* __restrict__ P1,
    const float* __restrict__ bo, float4* __restrict__ out) {
  for (int i = blockIdx.x * 256 + threadIdx.x; i < 1048576; i += 1024 * 256) {
    float4 a = P0[i], b = P1[i];
    float4 bb = *(const float4*)(bo + (i & 255) * 4);
    float4 o;
    o.x = a.x + b.x + bb.x; o.y = a.y + b.y + bb.y;
    o.z = a.z + b.z + bb.z; o.w = a.w + b.w + bb.w;
    out[i] = o;
  }
}

// ------------------------------------------------------------- attention
// Barrier-free, fragment-ordered inputs. Block = 64 q-rows; wave = 16 q-rows.
__global__ __launch_bounds__(256, 4) void attn_kernel(
    const unsigned short* __restrict__ Qf, const unsigned short* __restrict__ Kf,
    const unsigned short* __restrict__ Vf, unsigned short* __restrict__ Ctx) {
  __shared__ unsigned short Ps[4][16 * PSTR];
  const int p = blockIdx.x;
  const int bh = p & 31, qb0 = p >> 5;
  const int qb = (bh & 1) ? (31 - qb0) : qb0;
  const int b = bh >> 4, h = bh & 15;
  const int tid = threadIdx.x, wave = tid >> 6, lane = tid & 63;
  const int lm = lane & 15, quad = lane >> 4;
  const float L2E = 1.4426950408889634f;

  const int qbase = qb * 64 + wave * 16;
  const int nkw = qb + 1;

  bf16x8 qf[2];
#pragma unroll
  for (int c = 0; c < 2; ++c)
    qf[c] = *(const bf16x8*)(Qf +
        ((size_t)(bh * 128 + (qbase >> 4)) * 2 + c) * 512 + lane * 8);

  const unsigned short* Kb = Kf + (size_t)bh * 256 * 512;
  const unsigned short* Vb = Vf + (size_t)bh * 256 * 512;
  unsigned short* Pw = Ps[wave];

  float lsum = 0.f;
  f32x4 oacc[4];
#pragma unroll
  for (int a = 0; a < 4; ++a) {
    f32x4 z = {0.f, 0.f, 0.f, 0.f};
    oacc[a] = z;
  }

  for (int kt = 0; kt < nkw; ++kt) {
    bf16x8 kf[4][2];
#pragma unroll
    for (int ik = 0; ik < 4; ++ik)
#pragma unroll
      for (int c = 0; c < 2; ++c)
        kf[ik][c] = *(const bf16x8*)(Kb +
            ((size_t)(kt * 4 + ik) * 2 + c) * 512 + lane * 8);
    f32x4 s[4];
#pragma unroll
    for (int ik = 0; ik < 4; ++ik) {
      f32x4 z = {0.f, 0.f, 0.f, 0.f};
      z = __builtin_amdgcn_mfma_f32_16x16x32_bf16(kf[ik][0], qf[0], z, 0, 0, 0);
      s[ik] = __builtin_amdgcn_mfma_f32_16x16x32_bf16(kf[ik][1], qf[1], z, 0, 0, 0);
    }
    if (kt == nkw - 1) {
#pragma unroll
      for (int ik = 0; ik < 4; ++ik)
#pragma unroll
        for (int r = 0; r < 4; ++r) {
          int kg = kt * 64 + ik * 16 + quad * 4 + r;
          int qg = qbase + lm;
          if (kg > qg) s[ik][r] = -1e30f;
        }
    }

    bf16x8 vf[4][2];
#pragma unroll
    for (int a = 0; a < 4; ++a)
#pragma unroll
      for (int c = 0; c < 2; ++c)
        vf[a][c] = *(const bf16x8*)(Vb +
            ((size_t)(kt * 8 + a * 2 + c)) * 512 + lane * 8);

#pragma unroll
    for (int ik = 0; ik < 4; ++ik) {
      float p0 = fexp2(s[ik][0] * L2E);
      float p1 = fexp2(s[ik][1] * L2E);
      float p2 = fexp2(s[ik][2] * L2E);
      float p3 = fexp2(s[ik][3] * L2E);
      lsum += (p0 + p1) + (p2 + p3);
      uint2 w;
      w.x = pack_bf16(p0, p1);
      w.y = pack_bf16(p2, p3);
      *(uint2*)(Pw + lm * PSTR + ik * 16 + quad * 4) = w;
    }

    bf16x8 pf[2];
#pragma unroll
    for (int c = 0; c < 2; ++c)
      pf[c] = *(const bf16x8*)(Pw + lm * PSTR + c * 32 + quad * 8);
#pragma unroll
    for (int a = 0; a < 4; ++a) {
      oacc[a] = __builtin_amdgcn_mfma_f32_16x16x32_bf16(pf[0], vf[a][0], oacc[a], 0, 0, 0);
      oacc[a] = __builtin_amdgcn_mfma_f32_16x16x32_bf16(pf[1], vf[a][1], oacc[a], 0, 0, 0);
    }
  }

  lsum += __shfl_xor(lsum, 16);
  lsum += __shfl_xor(lsum, 32);
#pragma unroll
  for (int r = 0; r < 4; ++r) {
    float inv = 1.0f / __shfl(lsum, quad * 4 + r);
    int qg = qbase + quad * 4 + r;
#pragma unroll
    for (int a = 0; a < 4; ++a)
      Ctx[(size_t)(b * SS + qg) * DM + h * DK_ + a * 16 + lm] =
          f2bf_u(oacc[a][r] * inv);
  }
}

// ---------------------------------------------------------------- launch
extern "C" void kernel_launch(void* const* d_in, const int* in_sizes, int n_in,
                              void* d_out, int out_size, void* d_ws, size_t ws_size,
                              hipStream_t stream) {
  const float* q = (const float*)d_in[0];
  const float* k = (const float*)d_in[1];
  const float* v = (const float*)d_in[2];
  // d_in[3] = mask (fixed causal tril) — handled analytically
  const float* Wq = (const float*)d_in[4];
  const float* bq = (const float*)d_in[5];
  const float* Wk = (const float*)d_in[6];
  const float* bk = (const float*)d_in[7];
  const float* Wv = (const float*)d_in[8];
  const float* bv = (const float*)d_in[9];
  const float* Wo = (const float*)d_in[10];
  const float* bo = (const float*)d_in[11];

  const size_t NX = (size_t)BB * SS * DM;  // 4194304 shorts
  const size_t NW = (size_t)DM * DM;       // 1048576 shorts
  unsigned short* ws = (unsigned short*)d_ws;
  unsigned short* Wqb = ws;
  unsigned short* Wkb = Wqb + NW;
  unsigned short* Wvb = Wkb + NW;
  unsigned short* Wob = Wvb + NW;
  unsigned short* Qfr = Wob + NW;          // 4 NW = 8.39 MB
  unsigned short* Kfr = Qfr + NX;
  unsigned short* Vfr = Kfr + NX;
  unsigned short* Ctx = Vfr + NX;          // ends at 8.39 + 33.55 = 41.9 MB
  // split-K fp32 partials (16.78 MB each), both dead at o_gemm time:
  // P0 over (Qfr,Kfr) [8.39M, 25.2M); P1 past Ctx [41.9M, 58.7M).
  float* P0 = (float*)Qfr;
  float* P1 = (float*)(Ctx + NX);

  Cvt c;
  c.s[0] = Wq; c.s[1] = Wk; c.s[2] = Wv; c.s[3] = Wo;
  c.d[0] = Wqb; c.d[1] = Wkb; c.d[2] = Wvb; c.d[3] = Wob;

  dim3 blk(256);
  convert_kernel<<<dim3(256, 4), blk, 0, stream>>>(c);
  qkv_gemm<<<dim3(768), blk, 0, stream>>>(q, k, v, Wqb, Wkb, Wvb,
                                          bq, bk, bv, Qfr, Kfr, Vfr);
  attn_kernel<<<dim3(1024), blk, 0, stream>>>(Qfr, Kfr, Vfr, Ctx);
  o_gemm_sk<<<dim3(512), blk, 0, stream>>>(Ctx, Wob, P0, P1);
  o_reduce<<<dim3(1024), blk, 0, stream>>>((const float4*)P0, (const float4*)P1,
                                           bo, (float4*)d_out);
}

// Round 9
// 258.204 us; speedup vs baseline: 1.1326x; 1.1326x over previous
//
#include <hip/hip_runtime.h>
#include <hip/hip_bf16.h>
#include <stdint.h>

// MultiHeadAttention: B=2, S=2048, D=1024, H=16, DK=64, causal mask.
// R9: R7 structure (convert-all + global_load_lds GEMM staging + frag-ordered
// attn) + R8's validated XCD swizzle for qkv/o_gemm (c=p%8 owns 4 A-stripes;
// FETCH 101->49MB measured). R8's fused fp32-A staging reverted (it halved
// MfmaUtil via vmcnt-serialized VGPR->LDS writes + 8-way bank conflicts).

#define H_ 16
#define DM 1024
#define DK_ 64
#define BB 2
#define SS 2048
#define PSTR 72   // padded LDS stride (shorts) for P round-trip

typedef __bf16 bf16x8 __attribute__((ext_vector_type(8)));
typedef __bf16 bf16x2_t __attribute__((ext_vector_type(2)));
typedef float f32x4 __attribute__((ext_vector_type(4)));

#define GLOAD_LDS16(g, l)                                            \
  __builtin_amdgcn_global_load_lds(                                  \
      (__attribute__((address_space(1))) void*)(g),                  \
      (__attribute__((address_space(3))) void*)(l), 16, 0, 0)

__device__ __forceinline__ unsigned short f2bf_u(float f) {
  unsigned int u = __float_as_uint(f);
  u += 0x7fffu + ((u >> 16) & 1u);   // round-to-nearest-even
  return (unsigned short)(u >> 16);
}

__device__ __forceinline__ unsigned int pack_bf16(float a, float b) {
#if __has_builtin(__builtin_amdgcn_cvt_pk_bf16_f32)
  bf16x2_t v = __builtin_amdgcn_cvt_pk_bf16_f32(a, b);
  unsigned int u;
  __builtin_memcpy(&u, &v, 4);
  return u;
#else
  return (unsigned int)f2bf_u(a) | ((unsigned int)f2bf_u(b) << 16);
#endif
}

__device__ __forceinline__ float fexp2(float x) {
#if __has_builtin(__builtin_amdgcn_exp2f)
  return __builtin_amdgcn_exp2f(x);
#else
  return exp2f(x);
#endif
}

// ---------------------------------------------------------------- convert
struct Cvt {
  const float* s[7];
  unsigned short* d[7];
  int n[7];
};

__global__ __launch_bounds__(256) void convert_kernel(Cvt c) {
  const int y = blockIdx.y;
  const float* __restrict__ src = c.s[y];
  unsigned short* __restrict__ dst = c.d[y];
  const int nv = c.n[y] >> 2;
  for (int i = blockIdx.x * 256 + threadIdx.x; i < nv; i += 1024 * 256) {
    float4 v = *(const float4*)(src + (size_t)i * 4);
    ushort4 o;
    o.x = f2bf_u(v.x); o.y = f2bf_u(v.y); o.z = f2bf_u(v.z); o.w = f2bf_u(v.w);
    *(ushort4*)(dst + (size_t)i * 4) = o;
  }
}

// ------------------------------------------------------------- GEMM core
// C[128x128] = A[128xK] * W^T tile (NT layout), BK=32, K range [k0,k1).
template <int DUMMY = 0>
__device__ __forceinline__ void gemm_core(
    const unsigned short* __restrict__ A, const unsigned short* __restrict__ W,
    unsigned short* As, unsigned short* Bs, int m0, int n0, int k0, int k1,
    f32x4 (*acc)[4]) {
  const int tid = threadIdx.x;
  const int wave = tid >> 6, lane = tid & 63;
  const int lm = lane & 15, quad = lane >> 4;
  const int wm = (wave >> 1) * 64, wn = (wave & 1) * 64;
  const int srow = lane >> 2;
  const int scol = (lane & 3) * 8;

#pragma unroll
  for (int i = 0; i < 4; ++i)
#pragma unroll
    for (int j = 0; j < 4; ++j) {
      f32x4 z = {0.f, 0.f, 0.f, 0.f};
      acc[i][j] = z;
    }

  for (int kt = k0; kt < k1; kt += 32) {
#pragma unroll
    for (int cc = 0; cc < 2; ++cc) {
      int c = wave * 2 + cc;
      GLOAD_LDS16(A + (size_t)(m0 + c * 16 + srow) * DM + kt + scol,
                  As + c * 512 + lane * 8);
      GLOAD_LDS16(W + (size_t)(n0 + c * 16 + srow) * DM + kt + scol,
                  Bs + c * 512 + lane * 8);
    }
    __syncthreads();
    bf16x8 af[4], bfr[4];
#pragma unroll
    for (int i = 0; i < 4; ++i)
      af[i] = *(const bf16x8*)(As + (wm + i * 16 + lm) * 32 + quad * 8);
#pragma unroll
    for (int j = 0; j < 4; ++j)
      bfr[j] = *(const bf16x8*)(Bs + (wn + j * 16 + lm) * 32 + quad * 8);
#pragma unroll
    for (int i = 0; i < 4; ++i)
#pragma unroll
      for (int j = 0; j < 4; ++j)
        acc[i][j] = __builtin_amdgcn_mfma_f32_16x16x32_bf16(af[i], bfr[j],
                                                            acc[i][j], 0, 0, 0);
    __syncthreads();
  }
}

// fused Q/K/V projection, FRAGMENT-ORDERED outputs, XCD-swizzled grid.
// 1D grid 768: c=p%8 (XCD) owns A-stripes y in {4c..4c+3}; x,z swept within.
// Qf/Kf layout: block (bh*128 + s/16)*2 + d64/32, pos ((d64%32)/8*16+s%16)*8+d64%8.
// Vf layout: block ((bh*32+s/64)*4+dk/16)*2+(s%64)/32, pos ((s%32)/8*16+dk%16)*8+s%8.
__global__ __launch_bounds__(256) void qkv_gemm(
    const unsigned short* Qi, const unsigned short* Ki, const unsigned short* Vi,
    const unsigned short* Wq, const unsigned short* Wk, const unsigned short* Wv,
    const float* bq, const float* bk, const float* bv,
    unsigned short* Qf, unsigned short* Kf, unsigned short* Vf) {
  __shared__ unsigned short As[128 * 32], Bs[128 * 32];
  const int p = blockIdx.x;
  const int c = p & 7, jj0 = p >> 3;             // c = XCD
  const int x = jj0 & 7, yy = (jj0 >> 3) & 3, z = jj0 >> 5;
  const int y = c * 4 + yy;
  const int m0 = y * 128, n0 = x * 128;
  const unsigned short* A = z == 0 ? Qi : (z == 1 ? Ki : Vi);
  const unsigned short* W = z == 0 ? Wq : (z == 1 ? Wk : Wv);
  const float* bias = z == 0 ? bq : (z == 1 ? bk : bv);
  const float scale = z == 0 ? 0.125f : 1.0f;    // fold 1/sqrt(64) into Q
  f32x4 acc[4][4];
  gemm_core(A, W, As, Bs, m0, n0, 0, DM, acc);
  const int lane = threadIdx.x & 63, wave = threadIdx.x >> 6;
  const int lm = lane & 15, quad = lane >> 4;
  const int wm = (wave >> 1) * 64, wn = (wave & 1) * 64;
  if (z == 2) {
#pragma unroll
    for (int j = 0; j < 4; ++j) {
      int gn = n0 + wn + j * 16 + lm;
      float bv_ = bias[gn];
      int h2 = gn >> 6, dk = gn & 63;
      int a = dk >> 4, ln = dk & 15;
#pragma unroll
      for (int i = 0; i < 4; ++i) {
        int s0 = m0 + wm + i * 16 + quad * 4;    // 4 consecutive s
        int b2 = s0 >> 11, sl = s0 & 2047;
        int kt2 = sl >> 6, cc = (sl >> 5) & 1, qk = (sl >> 3) & 3, j0 = sl & 7;
        size_t base =
            ((size_t)(((b2 * 16 + h2) * 32 + kt2) * 4 + a) * 2 + cc) * 512 +
            (qk * 16 + ln) * 8 + j0;
        uint2 w;
        w.x = pack_bf16(acc[i][j][0] + bv_, acc[i][j][1] + bv_);
        w.y = pack_bf16(acc[i][j][2] + bv_, acc[i][j][3] + bv_);
        *(uint2*)(Vf + base) = w;
      }
    }
  } else {
    unsigned short* out = z == 0 ? Qf : Kf;
#pragma unroll
    for (int j = 0; j < 4; ++j) {
      int gn = n0 + wn + j * 16 + lm;
      float bv_ = bias[gn];
      int h2 = gn >> 6, d64 = gn & 63;
      int cc = (d64 >> 5) & 1, qk = (d64 >> 3) & 3, jjq = d64 & 7;
#pragma unroll
      for (int i = 0; i < 4; ++i)
#pragma unroll
        for (int r = 0; r < 4; ++r) {
          int gm = m0 + wm + i * 16 + quad * 4 + r;
          int b2 = gm >> 11, sl = gm & 2047;
          size_t base =
              ((size_t)((b2 * 16 + h2) * 128 + (sl >> 4)) * 2 + cc) * 512 +
              (qk * 16 + (sl & 15)) * 8 + jjq;
          out[base] = f2bf_u((acc[i][j][r] + bv_) * scale);
        }
    }
  }
}

// O-projection split-K, XCD-swizzled (c=p%8 owns 4 Ctx stripes).
__global__ __launch_bounds__(256) void o_gemm_sk(
    const unsigned short* Ctx, const unsigned short* Wo,
    float* P0, float* P1) {
  __shared__ unsigned short As[128 * 32], Bs[128 * 32];
  const int p = blockIdx.x;
  const int c = p & 7, jj0 = p >> 3;
  const int x = jj0 & 7, yy = (jj0 >> 3) & 3, ks = jj0 >> 5;
  const int y = c * 4 + yy;
  const int m0 = y * 128, n0 = x * 128;
  f32x4 acc[4][4];
  gemm_core(Ctx, Wo, As, Bs, m0, n0, ks * 512, ks * 512 + 512, acc);
  const int lane = threadIdx.x & 63, wave = threadIdx.x >> 6;
  const int lm = lane & 15, quad = lane >> 4;
  const int wm = (wave >> 1) * 64, wn = (wave & 1) * 64;
  float* dst = ks ? P1 : P0;
#pragma unroll
  for (int j = 0; j < 4; ++j) {
    int gn = n0 + wn + j * 16 + lm;
#pragma unroll
    for (int i = 0; i < 4; ++i)
#pragma unroll
      for (int r = 0; r < 4; ++r) {
        int gm = m0 + wm + i * 16 + quad * 4 + r;
        dst[(size_t)gm * DM + gn] = acc[i][j][r];
      }
  }
}

__global__ __launch_bounds__(256) void o_reduce(
    const float4* __restrict__ P0, const float4* __restrict__ P1,
    const float* __restrict__ bo, float4* __restrict__ out) {
  for (int i = blockIdx.x * 256 + threadIdx.x; i < 1048576; i += 1024 * 256) {
    float4 a = P0[i], b = P1[i];
    float4 bb = *(const float4*)(bo + (i & 255) * 4);
    float4 o;
    o.x = a.x + b.x + bb.x; o.y = a.y + b.y + bb.y;
    o.z = a.z + b.z + bb.z; o.w = a.w + b.w + bb.w;
    out[i] = o;
  }
}

// ------------------------------------------------------------- attention
// Barrier-free, fragment-ordered inputs. Block = 64 q-rows; wave = 16 q-rows.
// All global loads are coalesced 1KB wave-loads; only LDS use is the
// wave-private P round-trip (no __syncthreads anywhere).
__global__ __launch_bounds__(256, 4) void attn_kernel(
    const unsigned short* __restrict__ Qf, const unsigned short* __restrict__ Kf,
    const unsigned short* __restrict__ Vf, unsigned short* __restrict__ Ctx) {
  __shared__ unsigned short Ps[4][16 * PSTR];
  const int p = blockIdx.x;
  const int bh = p & 31, qb0 = p >> 5;
  const int qb = (bh & 1) ? (31 - qb0) : qb0;
  const int b = bh >> 4, h = bh & 15;
  const int tid = threadIdx.x, wave = tid >> 6, lane = tid & 63;
  const int lm = lane & 15, quad = lane >> 4;
  const float L2E = 1.4426950408889634f;

  const int qbase = qb * 64 + wave * 16;
  const int nkw = qb + 1;

  bf16x8 qf[2];
#pragma unroll
  for (int c = 0; c < 2; ++c)
    qf[c] = *(const bf16x8*)(Qf +
        ((size_t)(bh * 128 + (qbase >> 4)) * 2 + c) * 512 + lane * 8);

  const unsigned short* Kb = Kf + (size_t)bh * 256 * 512;
  const unsigned short* Vb = Vf + (size_t)bh * 256 * 512;
  unsigned short* Pw = Ps[wave];

  float lsum = 0.f;
  f32x4 oacc[4];
#pragma unroll
  for (int a = 0; a < 4; ++a) {
    f32x4 z = {0.f, 0.f, 0.f, 0.f};
    oacc[a] = z;
  }

  for (int kt = 0; kt < nkw; ++kt) {
    bf16x8 kf[4][2];
#pragma unroll
    for (int ik = 0; ik < 4; ++ik)
#pragma unroll
      for (int c = 0; c < 2; ++c)
        kf[ik][c] = *(const bf16x8*)(Kb +
            ((size_t)(kt * 4 + ik) * 2 + c) * 512 + lane * 8);
    f32x4 s[4];
#pragma unroll
    for (int ik = 0; ik < 4; ++ik) {
      f32x4 z = {0.f, 0.f, 0.f, 0.f};
      z = __builtin_amdgcn_mfma_f32_16x16x32_bf16(kf[ik][0], qf[0], z, 0, 0, 0);
      s[ik] = __builtin_amdgcn_mfma_f32_16x16x32_bf16(kf[ik][1], qf[1], z, 0, 0, 0);
    }
    if (kt == nkw - 1) {
#pragma unroll
      for (int ik = 0; ik < 4; ++ik)
#pragma unroll
        for (int r = 0; r < 4; ++r) {
          int kg = kt * 64 + ik * 16 + quad * 4 + r;
          int qg = qbase + lm;
          if (kg > qg) s[ik][r] = -1e30f;
        }
    }

    bf16x8 vf[4][2];
#pragma unroll
    for (int a = 0; a < 4; ++a)
#pragma unroll
      for (int c = 0; c < 2; ++c)
        vf[a][c] = *(const bf16x8*)(Vb +
            ((size_t)(kt * 8 + a * 2 + c)) * 512 + lane * 8);

#pragma unroll
    for (int ik = 0; ik < 4; ++ik) {
      float p0 = fexp2(s[ik][0] * L2E);
      float p1 = fexp2(s[ik][1] * L2E);
      float p2 = fexp2(s[ik][2] * L2E);
      float p3 = fexp2(s[ik][3] * L2E);
      lsum += (p0 + p1) + (p2 + p3);
      uint2 w;
      w.x = pack_bf16(p0, p1);
      w.y = pack_bf16(p2, p3);
      *(uint2*)(Pw + lm * PSTR + ik * 16 + quad * 4) = w;
    }

    bf16x8 pf[2];
#pragma unroll
    for (int c = 0; c < 2; ++c)
      pf[c] = *(const bf16x8*)(Pw + lm * PSTR + c * 32 + quad * 8);
#pragma unroll
    for (int a = 0; a < 4; ++a) {
      oacc[a] = __builtin_amdgcn_mfma_f32_16x16x32_bf16(pf[0], vf[a][0], oacc[a], 0, 0, 0);
      oacc[a] = __builtin_amdgcn_mfma_f32_16x16x32_bf16(pf[1], vf[a][1], oacc[a], 0, 0, 0);
    }
  }

  lsum += __shfl_xor(lsum, 16);
  lsum += __shfl_xor(lsum, 32);
#pragma unroll
  for (int r = 0; r < 4; ++r) {
    float inv = 1.0f / __shfl(lsum, quad * 4 + r);
    int qg = qbase + quad * 4 + r;
#pragma unroll
    for (int a = 0; a < 4; ++a)
      Ctx[(size_t)(b * SS + qg) * DM + h * DK_ + a * 16 + lm] =
          f2bf_u(oacc[a][r] * inv);
  }
}

// ---------------------------------------------------------------- launch
extern "C" void kernel_launch(void* const* d_in, const int* in_sizes, int n_in,
                              void* d_out, int out_size, void* d_ws, size_t ws_size,
                              hipStream_t stream) {
  const float* q = (const float*)d_in[0];
  const float* k = (const float*)d_in[1];
  const float* v = (const float*)d_in[2];
  // d_in[3] = mask (fixed causal tril) — handled analytically
  const float* Wq = (const float*)d_in[4];
  const float* bq = (const float*)d_in[5];
  const float* Wk = (const float*)d_in[6];
  const float* bk = (const float*)d_in[7];
  const float* Wv = (const float*)d_in[8];
  const float* bv = (const float*)d_in[9];
  const float* Wo = (const float*)d_in[10];
  const float* bo = (const float*)d_in[11];

  const size_t NX = (size_t)BB * SS * DM;  // 4194304 shorts
  const size_t NW = (size_t)DM * DM;       // 1048576 shorts
  unsigned short* ws = (unsigned short*)d_ws;
  unsigned short* Qi = ws;
  unsigned short* Ki = Qi + NX;
  unsigned short* Vi = Ki + NX;
  unsigned short* Wqb = Vi + NX;
  unsigned short* Wkb = Wqb + NW;
  unsigned short* Wvb = Wkb + NW;
  unsigned short* Wob = Wvb + NW;
  unsigned short* Qfr = Wob + NW;
  unsigned short* Kfr = Qfr + NX;
  unsigned short* Vfr = Kfr + NX;
  unsigned short* Ctx = Vfr + NX;
  // split-K fp32 partials over regions dead at o_gemm time:
  // P0 over (Qi,Ki) bytes [0,16.78M); P1 over (Qfr,Kfr) [33.55M,50.33M).
  float* P0 = (float*)ws;
  float* P1 = (float*)Qfr;

  Cvt c;
  c.s[0] = q; c.s[1] = k; c.s[2] = v; c.s[3] = Wq; c.s[4] = Wk; c.s[5] = Wv; c.s[6] = Wo;
  c.d[0] = Qi; c.d[1] = Ki; c.d[2] = Vi; c.d[3] = Wqb; c.d[4] = Wkb; c.d[5] = Wvb; c.d[6] = Wob;
  c.n[0] = c.n[1] = c.n[2] = (int)NX;
  c.n[3] = c.n[4] = c.n[5] = c.n[6] = (int)NW;

  dim3 blk(256);
  convert_kernel<<<dim3(1024, 7), blk, 0, stream>>>(c);
  qkv_gemm<<<dim3(768), blk, 0, stream>>>(Qi, Ki, Vi, Wqb, Wkb, Wvb,
                                          bq, bk, bv, Qfr, Kfr, Vfr);
  attn_kernel<<<dim3(1024), blk, 0, stream>>>(Qfr, Kfr, Vfr, Ctx);
  o_gemm_sk<<<dim3(512), blk, 0, stream>>>(Ctx, Wob, P0, P1);
  o_reduce<<<dim3(1024), blk, 0, stream>>>((const float4*)P0, (const float4*)P1,
                                           bo, (float4*)d_out);
}

// Round 10
// 257.112 us; speedup vs baseline: 1.1374x; 1.0042x over previous
//
#include <hip/hip_runtime.h>
#include <hip/hip_bf16.h>
#include <stdint.h>

// MultiHeadAttention: B=2, S=2048, D=1024, H=16, DK=64, causal mask.
// R10: gemm_dbuf — double-buffered LDS with loads issued AFTER the barrier
// (latency covered by compute; 1 barrier/iter instead of 2 with a vmcnt(0)
// drain each). Direct o_gemm (128x64, K=1024, fused bias) replaces split-K +
// o_reduce. XCD swizzle kept (R9-validated). attn/convert unchanged.

#define H_ 16
#define DM 1024
#define DK_ 64
#define BB 2
#define SS 2048
#define PSTR 72   // padded LDS stride (shorts) for P round-trip

typedef __bf16 bf16x8 __attribute__((ext_vector_type(8)));
typedef __bf16 bf16x2_t __attribute__((ext_vector_type(2)));
typedef float f32x4 __attribute__((ext_vector_type(4)));

#define GLOAD_LDS16(g, l)                                            \
  __builtin_amdgcn_global_load_lds(                                  \
      (__attribute__((address_space(1))) void*)(g),                  \
      (__attribute__((address_space(3))) void*)(l), 16, 0, 0)

__device__ __forceinline__ unsigned short f2bf_u(float f) {
  unsigned int u = __float_as_uint(f);
  u += 0x7fffu + ((u >> 16) & 1u);   // round-to-nearest-even
  return (unsigned short)(u >> 16);
}

__device__ __forceinline__ unsigned int pack_bf16(float a, float b) {
#if __has_builtin(__builtin_amdgcn_cvt_pk_bf16_f32)
  bf16x2_t v = __builtin_amdgcn_cvt_pk_bf16_f32(a, b);
  unsigned int u;
  __builtin_memcpy(&u, &v, 4);
  return u;
#else
  return (unsigned int)f2bf_u(a) | ((unsigned int)f2bf_u(b) << 16);
#endif
}

__device__ __forceinline__ float fexp2(float x) {
#if __has_builtin(__builtin_amdgcn_exp2f)
  return __builtin_amdgcn_exp2f(x);
#else
  return exp2f(x);
#endif
}

// ---------------------------------------------------------------- convert
struct Cvt {
  const float* s[7];
  unsigned short* d[7];
  int n[7];
};

__global__ __launch_bounds__(256) void convert_kernel(Cvt c) {
  const int y = blockIdx.y;
  const float* __restrict__ src = c.s[y];
  unsigned short* __restrict__ dst = c.d[y];
  const int nv = c.n[y] >> 2;
  for (int i = blockIdx.x * 256 + threadIdx.x; i < nv; i += 1024 * 256) {
    float4 v = *(const float4*)(src + (size_t)i * 4);
    ushort4 o;
    o.x = f2bf_u(v.x); o.y = f2bf_u(v.y); o.z = f2bf_u(v.z); o.w = f2bf_u(v.w);
    *(ushort4*)(dst + (size_t)i * 4) = o;
  }
}

// ------------------------------------------------- GEMM core, double-buffered
// C[128xTN] = A[128x1024] * W^T tile (NT layout), BK=32.
// K-loop shape: barrier(tile kt resident) -> issue loads(kt+1, other buffer)
// -> compute(kt). Loads have the whole compute phase to land; the compiler's
// vmcnt(0)-before-barrier drain is then nearly free. One barrier per iter.
template <int TN>
__device__ __forceinline__ void gemm_dbuf(
    const unsigned short* __restrict__ A, const unsigned short* __restrict__ W,
    unsigned short* As, unsigned short* Bs, int m0, int n0,
    f32x4 (*acc)[TN / 32]) {
  constexpr int FW = TN / 32;
  const int tid = threadIdx.x;
  const int wave = tid >> 6, lane = tid & 63;
  const int lm = lane & 15, quad = lane >> 4;
  const int wm = (wave >> 1) * 64, wn = (wave & 1) * (16 * FW);
  const int srow = lane >> 2;
  const int scol = (lane & 3) * 8;

#pragma unroll
  for (int i = 0; i < 4; ++i)
#pragma unroll
    for (int j = 0; j < FW; ++j) {
      f32x4 z = {0.f, 0.f, 0.f, 0.f};
      acc[i][j] = z;
    }

  // stage tile 0 into buffer 0
#pragma unroll
  for (int cc = 0; cc < 2; ++cc) {
    int c = wave * 2 + cc;
    GLOAD_LDS16(A + (size_t)(m0 + c * 16 + srow) * DM + scol,
                As + c * 512 + lane * 8);
  }
  if (TN == 128) {
#pragma unroll
    for (int cc = 0; cc < 2; ++cc) {
      int c = wave * 2 + cc;
      GLOAD_LDS16(W + (size_t)(n0 + c * 16 + srow) * DM + scol,
                  Bs + c * 512 + lane * 8);
    }
  } else {
    GLOAD_LDS16(W + (size_t)(n0 + wave * 16 + srow) * DM + scol,
                Bs + wave * 512 + lane * 8);
  }

  for (int kt = 0; kt < DM / 32; ++kt) {
    __syncthreads();                          // tile kt resident
    const int cur = kt & 1;
    const unsigned short* Ac = As + cur * (128 * 32);
    const unsigned short* Bc = Bs + cur * (TN * 32);
    if (kt + 1 < DM / 32) {                   // prefetch kt+1 (other buffer)
      unsigned short* An = As + (cur ^ 1) * (128 * 32);
      unsigned short* Bn = Bs + (cur ^ 1) * (TN * 32);
      const int kcol = (kt + 1) * 32 + scol;
#pragma unroll
      for (int cc = 0; cc < 2; ++cc) {
        int c = wave * 2 + cc;
        GLOAD_LDS16(A + (size_t)(m0 + c * 16 + srow) * DM + kcol,
                    An + c * 512 + lane * 8);
      }
      if (TN == 128) {
#pragma unroll
        for (int cc = 0; cc < 2; ++cc) {
          int c = wave * 2 + cc;
          GLOAD_LDS16(W + (size_t)(n0 + c * 16 + srow) * DM + kcol,
                      Bn + c * 512 + lane * 8);
        }
      } else {
        GLOAD_LDS16(W + (size_t)(n0 + wave * 16 + srow) * DM + kcol,
                    Bn + wave * 512 + lane * 8);
      }
    }
    bf16x8 af[4], bfr[FW];
#pragma unroll
    for (int i = 0; i < 4; ++i)
      af[i] = *(const bf16x8*)(Ac + (wm + i * 16 + lm) * 32 + quad * 8);
#pragma unroll
    for (int j = 0; j < FW; ++j)
      bfr[j] = *(const bf16x8*)(Bc + (wn + j * 16 + lm) * 32 + quad * 8);
#pragma unroll
    for (int i = 0; i < 4; ++i)
#pragma unroll
      for (int j = 0; j < FW; ++j)
        acc[i][j] = __builtin_amdgcn_mfma_f32_16x16x32_bf16(af[i], bfr[j],
                                                            acc[i][j], 0, 0, 0);
  }
}

// fused Q/K/V projection, FRAGMENT-ORDERED outputs, XCD-swizzled grid.
// 1D grid 768: c=p%8 (XCD) owns A-stripes y in {4c..4c+3}; x,z swept within.
__global__ __launch_bounds__(256) void qkv_gemm(
    const unsigned short* Qi, const unsigned short* Ki, const unsigned short* Vi,
    const unsigned short* Wq, const unsigned short* Wk, const unsigned short* Wv,
    const float* bq, const float* bk, const float* bv,
    unsigned short* Qf, unsigned short* Kf, unsigned short* Vf) {
  __shared__ unsigned short As[2 * 128 * 32], Bs[2 * 128 * 32];
  const int p = blockIdx.x;
  const int c = p & 7, jj0 = p >> 3;             // c = XCD
  const int x = jj0 & 7, yy = (jj0 >> 3) & 3, z = jj0 >> 5;
  const int y = c * 4 + yy;
  const int m0 = y * 128, n0 = x * 128;
  const unsigned short* A = z == 0 ? Qi : (z == 1 ? Ki : Vi);
  const unsigned short* W = z == 0 ? Wq : (z == 1 ? Wk : Wv);
  const float* bias = z == 0 ? bq : (z == 1 ? bk : bv);
  const float scale = z == 0 ? 0.125f : 1.0f;    // fold 1/sqrt(64) into Q
  f32x4 acc[4][4];
  gemm_dbuf<128>(A, W, As, Bs, m0, n0, acc);
  const int lane = threadIdx.x & 63, wave = threadIdx.x >> 6;
  const int lm = lane & 15, quad = lane >> 4;
  const int wm = (wave >> 1) * 64, wn = (wave & 1) * 64;
  if (z == 2) {
#pragma unroll
    for (int j = 0; j < 4; ++j) {
      int gn = n0 + wn + j * 16 + lm;
      float bv_ = bias[gn];
      int h2 = gn >> 6, dk = gn & 63;
      int a = dk >> 4, ln = dk & 15;
#pragma unroll
      for (int i = 0; i < 4; ++i) {
        int s0 = m0 + wm + i * 16 + quad * 4;    // 4 consecutive s
        int b2 = s0 >> 11, sl = s0 & 2047;
        int kt2 = sl >> 6, cc = (sl >> 5) & 1, qk = (sl >> 3) & 3, j0 = sl & 7;
        size_t base =
            ((size_t)(((b2 * 16 + h2) * 32 + kt2) * 4 + a) * 2 + cc) * 512 +
            (qk * 16 + ln) * 8 + j0;
        uint2 w;
        w.x = pack_bf16(acc[i][j][0] + bv_, acc[i][j][1] + bv_);
        w.y = pack_bf16(acc[i][j][2] + bv_, acc[i][j][3] + bv_);
        *(uint2*)(Vf + base) = w;
      }
    }
  } else {
    unsigned short* out = z == 0 ? Qf : Kf;
#pragma unroll
    for (int j = 0; j < 4; ++j) {
      int gn = n0 + wn + j * 16 + lm;
      float bv_ = bias[gn];
      int h2 = gn >> 6, d64 = gn & 63;
      int cc = (d64 >> 5) & 1, qk = (d64 >> 3) & 3, jjq = d64 & 7;
#pragma unroll
      for (int i = 0; i < 4; ++i)
#pragma unroll
        for (int r = 0; r < 4; ++r) {
          int gm = m0 + wm + i * 16 + quad * 4 + r;
          int b2 = gm >> 11, sl = gm & 2047;
          size_t base =
              ((size_t)((b2 * 16 + h2) * 128 + (sl >> 4)) * 2 + cc) * 512 +
              (qk * 16 + (sl & 15)) * 8 + jjq;
          out[base] = f2bf_u((acc[i][j][r] + bv_) * scale);
        }
    }
  }
}

// O-projection, direct: 128x64 tiles, full K, fused bias, fp32 out.
// 512 blocks XCD-swizzled: c=p%8 owns Ctx stripes y in {4c..4c+3} (x 0..15).
__global__ __launch_bounds__(256) void o_gemm(
    const unsigned short* Ctx, const unsigned short* Wo, const float* bo,
    float* out) {
  __shared__ unsigned short As[2 * 128 * 32], Bs[2 * 64 * 32];
  const int p = blockIdx.x;
  const int c = p & 7, j0 = p >> 3;              // j0 0..63
  const int x = j0 & 15, yy = j0 >> 4;           // x 0..15, yy 0..3
  const int y = c * 4 + yy;
  const int m0 = y * 128, n0 = x * 64;
  f32x4 acc[4][2];
  gemm_dbuf<64>(Ctx, Wo, As, Bs, m0, n0, acc);
  const int lane = threadIdx.x & 63, wave = threadIdx.x >> 6;
  const int lm = lane & 15, quad = lane >> 4;
  const int wm = (wave >> 1) * 64, wn = (wave & 1) * 32;
#pragma unroll
  for (int j = 0; j < 2; ++j) {
    int gn = n0 + wn + j * 16 + lm;
    float bv_ = bo[gn];
#pragma unroll
    for (int i = 0; i < 4; ++i)
#pragma unroll
      for (int r = 0; r < 4; ++r) {
        int gm = m0 + wm + i * 16 + quad * 4 + r;
        out[(size_t)gm * DM + gn] = acc[i][j][r] + bv_;
      }
  }
}

// ------------------------------------------------------------- attention
// Barrier-free, fragment-ordered inputs. Block = 64 q-rows; wave = 16 q-rows.
__global__ __launch_bounds__(256, 4) void attn_kernel(
    const unsigned short* __restrict__ Qf, const unsigned short* __restrict__ Kf,
    const unsigned short* __restrict__ Vf, unsigned short* __restrict__ Ctx) {
  __shared__ unsigned short Ps[4][16 * PSTR];
  const int p = blockIdx.x;
  const int bh = p & 31, qb0 = p >> 5;
  const int qb = (bh & 1) ? (31 - qb0) : qb0;
  const int b = bh >> 4, h = bh & 15;
  const int tid = threadIdx.x, wave = tid >> 6, lane = tid & 63;
  const int lm = lane & 15, quad = lane >> 4;
  const float L2E = 1.4426950408889634f;

  const int qbase = qb * 64 + wave * 16;
  const int nkw = qb + 1;

  bf16x8 qf[2];
#pragma unroll
  for (int c = 0; c < 2; ++c)
    qf[c] = *(const bf16x8*)(Qf +
        ((size_t)(bh * 128 + (qbase >> 4)) * 2 + c) * 512 + lane * 8);

  const unsigned short* Kb = Kf + (size_t)bh * 256 * 512;
  const unsigned short* Vb = Vf + (size_t)bh * 256 * 512;
  unsigned short* Pw = Ps[wave];

  float lsum = 0.f;
  f32x4 oacc[4];
#pragma unroll
  for (int a = 0; a < 4; ++a) {
    f32x4 z = {0.f, 0.f, 0.f, 0.f};
    oacc[a] = z;
  }

  for (int kt = 0; kt < nkw; ++kt) {
    bf16x8 kf[4][2];
#pragma unroll
    for (int ik = 0; ik < 4; ++ik)
#pragma unroll
      for (int c = 0; c < 2; ++c)
        kf[ik][c] = *(const bf16x8*)(Kb +
            ((size_t)(kt * 4 + ik) * 2 + c) * 512 + lane * 8);
    f32x4 s[4];
#pragma unroll
    for (int ik = 0; ik < 4; ++ik) {
      f32x4 z = {0.f, 0.f, 0.f, 0.f};
      z = __builtin_amdgcn_mfma_f32_16x16x32_bf16(kf[ik][0], qf[0], z, 0, 0, 0);
      s[ik] = __builtin_amdgcn_mfma_f32_16x16x32_bf16(kf[ik][1], qf[1], z, 0, 0, 0);
    }
    if (kt == nkw - 1) {
#pragma unroll
      for (int ik = 0; ik < 4; ++ik)
#pragma unroll
        for (int r = 0; r < 4; ++r) {
          int kg = kt * 64 + ik * 16 + quad * 4 + r;
          int qg = qbase + lm;
          if (kg > qg) s[ik][r] = -1e30f;
        }
    }

    bf16x8 vf[4][2];
#pragma unroll
    for (int a = 0; a < 4; ++a)
#pragma unroll
      for (int c = 0; c < 2; ++c)
        vf[a][c] = *(const bf16x8*)(Vb +
            ((size_t)(kt * 8 + a * 2 + c)) * 512 + lane * 8);

#pragma unroll
    for (int ik = 0; ik < 4; ++ik) {
      float p0 = fexp2(s[ik][0] * L2E);
      float p1 = fexp2(s[ik][1] * L2E);
      float p2 = fexp2(s[ik][2] * L2E);
      float p3 = fexp2(s[ik][3] * L2E);
      lsum += (p0 + p1) + (p2 + p3);
      uint2 w;
      w.x = pack_bf16(p0, p1);
      w.y = pack_bf16(p2, p3);
      *(uint2*)(Pw + lm * PSTR + ik * 16 + quad * 4) = w;
    }

    bf16x8 pf[2];
#pragma unroll
    for (int c = 0; c < 2; ++c)
      pf[c] = *(const bf16x8*)(Pw + lm * PSTR + c * 32 + quad * 8);
#pragma unroll
    for (int a = 0; a < 4; ++a) {
      oacc[a] = __builtin_amdgcn_mfma_f32_16x16x32_bf16(pf[0], vf[a][0], oacc[a], 0, 0, 0);
      oacc[a] = __builtin_amdgcn_mfma_f32_16x16x32_bf16(pf[1], vf[a][1], oacc[a], 0, 0, 0);
    }
  }

  lsum += __shfl_xor(lsum, 16);
  lsum += __shfl_xor(lsum, 32);
#pragma unroll
  for (int r = 0; r < 4; ++r) {
    float inv = 1.0f / __shfl(lsum, quad * 4 + r);
    int qg = qbase + quad * 4 + r;
#pragma unroll
    for (int a = 0; a < 4; ++a)
      Ctx[(size_t)(b * SS + qg) * DM + h * DK_ + a * 16 + lm] =
          f2bf_u(oacc[a][r] * inv);
  }
}

// ---------------------------------------------------------------- launch
extern "C" void kernel_launch(void* const* d_in, const int* in_sizes, int n_in,
                              void* d_out, int out_size, void* d_ws, size_t ws_size,
                              hipStream_t stream) {
  const float* q = (const float*)d_in[0];
  const float* k = (const float*)d_in[1];
  const float* v = (const float*)d_in[2];
  // d_in[3] = mask (fixed causal tril) — handled analytically
  const float* Wq = (const float*)d_in[4];
  const float* bq = (const float*)d_in[5];
  const float* Wk = (const float*)d_in[6];
  const float* bk = (const float*)d_in[7];
  const float* Wv = (const float*)d_in[8];
  const float* bv = (const float*)d_in[9];
  const float* Wo = (const float*)d_in[10];
  const float* bo = (const float*)d_in[11];

  const size_t NX = (size_t)BB * SS * DM;  // 4194304 shorts
  const size_t NW = (size_t)DM * DM;       // 1048576 shorts
  unsigned short* ws = (unsigned short*)d_ws;
  unsigned short* Qi = ws;
  unsigned short* Ki = Qi + NX;
  unsigned short* Vi = Ki + NX;
  unsigned short* Wqb = Vi + NX;
  unsigned short* Wkb = Wqb + NW;
  unsigned short* Wvb = Wkb + NW;
  unsigned short* Wob = Wvb + NW;
  unsigned short* Qfr = Wob + NW;
  unsigned short* Kfr = Qfr + NX;
  unsigned short* Vfr = Kfr + NX;
  unsigned short* Ctx = Vfr + NX;

  Cvt c;
  c.s[0] = q; c.s[1] = k; c.s[2] = v; c.s[3] = Wq; c.s[4] = Wk; c.s[5] = Wv; c.s[6] = Wo;
  c.d[0] = Qi; c.d[1] = Ki; c.d[2] = Vi; c.d[3] = Wqb; c.d[4] = Wkb; c.d[5] = Wvb; c.d[6] = Wob;
  c.n[0] = c.n[1] = c.n[2] = (int)NX;
  c.n[3] = c.n[4] = c.n[5] = c.n[6] = (int)NW;

  dim3 blk(256);
  convert_kernel<<<dim3(1024, 7), blk, 0, stream>>>(c);
  qkv_gemm<<<dim3(768), blk, 0, stream>>>(Qi, Ki, Vi, Wqb, Wkb, Wvb,
                                          bq, bk, bv, Qfr, Kfr, Vfr);
  attn_kernel<<<dim3(1024), blk, 0, stream>>>(Qfr, Kfr, Vfr, Ctx);
  o_gemm<<<dim3(512), blk, 0, stream>>>(Ctx, Wob, bo, (float*)d_out);
}